// Round 1
// 586.364 us; speedup vs baseline: 1.0682x; 1.0682x over previous
//
#include <hip/hip_runtime.h>
#include <cstddef>

#define Nn 1024
#define Bb 32
#define Ff 128
#define Vv 32768            // B*N
#define MAT 33554432        // B*N*N
#define OUT_OFF 0
#define AC_OFF 8192
#define OA_OFF (8192 + 33554432)
#define MC_OFF (OA_OFF + 128)
#define OR_OFF (MC_OFF + 1)
#define EPSf 1e-15f
#define MUf 0.01f

__device__ __forceinline__ float wave_sum(float v) {
    #pragma unroll
    for (int off = 32; off; off >>= 1) v += __shfl_xor(v, off, 64);
    return v;
}
__device__ __forceinline__ float wave_max(float v) {
    #pragma unroll
    for (int off = 32; off; off >>= 1) v = fmaxf(v, __shfl_xor(v, off, 64));
    return v;
}

// bf16 helpers (RNE pack, exact expand)
__device__ __forceinline__ ushort f2bf(float f) {
    unsigned u = __float_as_uint(f);
    u = (u + 0x7fffu + ((u >> 16) & 1u)) >> 16;
    return (ushort)u;
}
__device__ __forceinline__ unsigned pack2(float a, float b) {
    return (unsigned)f2bf(a) | ((unsigned)f2bf(b) << 16);
}
__device__ __forceinline__ void bf8_to_f32(uint4 v, float* f) {
    f[0] = __uint_as_float(v.x << 16); f[1] = __uint_as_float(v.x & 0xffff0000u);
    f[2] = __uint_as_float(v.y << 16); f[3] = __uint_as_float(v.y & 0xffff0000u);
    f[4] = __uint_as_float(v.z << 16); f[5] = __uint_as_float(v.z & 0xffff0000u);
    f[6] = __uint_as_float(v.w << 16); f[7] = __uint_as_float(v.w & 0xffff0000u);
}

// ---- K1: row sums of adj -> d_flat, fused per-node vectors ----
__global__ void k_rowsumvec(const float* __restrict__ adj, const float* __restrict__ s_in,
                            float* __restrict__ dflat,
                            float* __restrict__ s0a, float* __restrict__ s1a,
                            float* __restrict__ ua, float* __restrict__ uoda,
                            float* __restrict__ d2a, float* __restrict__ ddera) {
    int w = threadIdx.x >> 6, lane = threadIdx.x & 63;
    int row = blockIdx.x * 4 + w;          // 0..32767
    const float* r = adj + (size_t)row * Nn;
    float acc = 0.f;
    #pragma unroll
    for (int cc = 0; cc < 4; ++cc) {
        float4 v = *(const float4*)(r + cc * 256 + (lane << 2));
        acc += v.x + v.y + v.z + v.w;
    }
    acc = wave_sum(acc);
    if (lane == 0) {
        float df = acc;
        dflat[row] = df;
        float l0 = s_in[2 * row], l1 = s_in[2 * row + 1];
        float m = fmaxf(l0, l1);
        float e0 = __expf(l0 - m), e1 = __expf(l1 - m);
        float Z = e0 + e1;
        s0a[row] = e0 / Z; s1a[row] = e1 / Z;
        float u = (l1 > l0) ? -0.03125f : 0.03125f;
        float d2 = sqrtf(df + EPSf) + EPSf;
        float uod = u / d2;
        ua[row] = u; uoda[row] = uod; d2a[row] = d2;
        ddera[row] = -0.5f * d2 / (df + EPSf);
    }
}

// ---- K3: per-row matvecs r1=A.uod r2=A.u q1=A.s0 q2=A.s1. wave per row ----
__global__ void k_matvec(const float* __restrict__ adj,
                         const float* __restrict__ uoda, const float* __restrict__ ua,
                         const float* __restrict__ s0a, const float* __restrict__ s1a,
                         float* __restrict__ r1a, float* __restrict__ r2a,
                         float* __restrict__ q1a, float* __restrict__ q2a) {
    int w = threadIdx.x >> 6, lane = threadIdx.x & 63;
    int row = blockIdx.x * 4 + w;
    int b = row >> 10;
    const float* r = adj + (size_t)row * Nn;
    const float* uodB = uoda + b * Nn;
    const float* uB = ua + b * Nn;
    const float* s0B = s0a + b * Nn;
    const float* s1B = s1a + b * Nn;
    float a1 = 0.f, a2 = 0.f, a3 = 0.f, a4 = 0.f;
    #pragma unroll
    for (int cc = 0; cc < 4; ++cc) {
        int j0 = cc * 256 + (lane << 2);
        float4 av = *(const float4*)(r + j0);
        float4 uo = *(const float4*)(uodB + j0);
        float4 uu = *(const float4*)(uB + j0);
        float4 v0 = *(const float4*)(s0B + j0);
        float4 v1 = *(const float4*)(s1B + j0);
        a1 += av.x * uo.x + av.y * uo.y + av.z * uo.z + av.w * uo.w;
        a2 += av.x * uu.x + av.y * uu.y + av.z * uu.z + av.w * uu.w;
        a3 += av.x * v0.x + av.y * v0.y + av.z * v0.z + av.w * v0.w;
        a4 += av.x * v1.x + av.y * v1.y + av.z * v1.z + av.w * v1.w;
    }
    a1 = wave_sum(a1); a2 = wave_sum(a2); a3 = wave_sum(a3); a4 = wave_sum(a4);
    if (lane == 0) { r1a[row] = a1; r2a[row] = a2; q1a[row] = a3; q2a[row] = a4; }
}

// ---- K4: per-batch reductions -> f, coefP, m8f, out_adj, loss parts ----
__global__ void k_batchred(const float* __restrict__ dflat, const float* __restrict__ s0a,
                           const float* __restrict__ s1a, const float* __restrict__ ua,
                           const float* __restrict__ uoda, const float* __restrict__ d2a,
                           const float* __restrict__ r1a, const float* __restrict__ r2a,
                           const float* __restrict__ q1a, const float* __restrict__ q2a,
                           float* __restrict__ outp, float* __restrict__ coefP,
                           float* __restrict__ m8f, float* __restrict__ mcp,
                           float* __restrict__ orp) {
    int b = blockIdx.x, t = threadIdx.x;
    int base = b * Nn;
    float acc[13];
    #pragma unroll
    for (int k = 0; k < 13; ++k) acc[k] = 0.f;
    for (int i = t; i < Nn; i += 256) {
        float u = ua[base + i], uod = uoda[base + i], df = dflat[base + i], d2 = d2a[base + i];
        float r1 = r1a[base + i], r2 = r2a[base + i], q1 = q1a[base + i], q2 = q2a[base + i];
        float s0 = s0a[base + i], s1 = s1a[base + i];
        acc[0] += u * r1;
        acc[1] += uod * r2;
        acc[2] += df * uod * uod;
        acc[3] += uod * r1;
        acc[4] += d2 * d2 * (1.0f / 1024.0f);
        acc[5] += s0 * q1;
        acc[6] += s0 * q2;
        acc[7] += s1 * q1;
        acc[8] += s1 * q2;
        acc[9] += df * (s0 * s0 + s1 * s1);
        acc[10] += s0 * s0;
        acc[11] += s0 * s1;
        acc[12] += s1 * s1;
    }
    __shared__ float red[4][13];
    int w = t >> 6, lane = t & 63;
    #pragma unroll
    for (int k = 0; k < 13; ++k) {
        acc[k] = wave_sum(acc[k]);
        if (lane == 0) red[w][k] = acc[k];
    }
    __syncthreads();
    if (t == 0) {
        float v[13];
        #pragma unroll
        for (int k = 0; k < 13; ++k) v[k] = red[0][k] + red[1][k] + red[2][k] + red[3][k];
        float num = v[2] - v[3];
        float f = 1024.0f * fabsf(num / (v[4] + EPSf));
        float as = v[0] + v[1];
        coefP[b] = -4.0f * f * as;
        m8f[b] = -8.0f * f;
        outp[OA_OFF + b * 4 + 0] = v[5];
        outp[OA_OFF + b * 4 + 1] = v[6];
        outp[OA_OFF + b * 4 + 2] = v[7];
        outp[OA_OFF + b * 4 + 3] = v[8];
        mcp[b] = -((v[5] + v[8]) / v[9]);
        float ss00 = v[10], ss01 = v[11], ss11 = v[12];
        float nrm = sqrtf(ss00 * ss00 + 2.f * ss01 * ss01 + ss11 * ss11);
        float is = 0.7071067811865475f;
        float d00 = ss00 / nrm - is, d01 = ss01 / nrm, d11 = ss11 / nrm - is;
        orp[b] = sqrtf(d00 * d00 + 2.f * d01 * d01 + d11 * d11);
    }
}

// ---- K4b: average loss parts ----
__global__ void k_final(const float* __restrict__ mcp, const float* __restrict__ orp,
                        float* __restrict__ outp) {
    int t = threadIdx.x;  // 64
    float m = (t < 32) ? mcp[t] : 0.f;
    float o = (t < 32) ? orp[t] : 0.f;
    m = wave_sum(m); o = wave_sum(o);
    if (t == 0) { outp[MC_OFF] = m * (1.0f / 32.0f); outp[OR_OFF] = o * (1.0f / 32.0f); }
}

// ---- K5a: pooled feature partials. 64 chunks of 16 rows per batch ----
__global__ void k_pool_a(const float* __restrict__ x, const float* __restrict__ s0a,
                         const float* __restrict__ s1a, float* __restrict__ pp) {
    int c = blockIdx.x, b = blockIdx.y, f = threadIdx.x;  // 64 x 32, 128 threads
    const float* xb = x + (size_t)b * Nn * Ff;
    float a0 = 0.f, a1 = 0.f;
    int n0 = c * 16;
    #pragma unroll 4
    for (int n = n0; n < n0 + 16; ++n) {
        float xv = xb[(size_t)n * Ff + f];
        a0 += s0a[b * Nn + n] * xv;
        a1 += s1a[b * Nn + n] * xv;
    }
    pp[((size_t)(b * 64 + c) * 2 + 0) * Ff + f] = a0;
    pp[((size_t)(b * 64 + c) * 2 + 1) * Ff + f] = a1;
}

// ---- K5b: reduce pooled partials -> d_out ----
__global__ void k_pool_b(const float* __restrict__ pp, float* __restrict__ outp) {
    int b = blockIdx.x, t = threadIdx.x;  // 256
    int k = t >> 7, f = t & 127;
    float acc = 0.f;
    #pragma unroll
    for (int c = 0; c < 64; ++c) acc += pp[((size_t)(b * 64 + c) * 2 + k) * Ff + f];
    outp[OUT_OFF + b * 256 + k * Ff + f] = acc;
}

// ---- K6: one rewiring iteration.
// Inter-iteration state S = Ac - adj stored in BF16, panel layout:
//   S[b,i,j] at ushort index b*N*N + (i>>3)*8192 + (i&7)*1024 + j
// i.e. row-major 8x1024 panels. A wave's own row is contiguous -> direct
// coalesced global load + store, no LDS needed for the row side or the
// output transpose. Only the transposed slice T (8 cols of the block's
// rows, bf16, 16.5 KB) is staged in LDS. One barrier per launch.
// XCD swizzle: all 128 blocks of a batch land on one XCD (L2 locality for
// the T column-slice reads).
__global__ __launch_bounds__(512, 6) void k_iter(
    const ushort* __restrict__ Ssrc,   // bf16 panel layout; null on iter 1
    ushort* __restrict__ Sdst,         // bf16 panel layout (iters 1-4)
    float* __restrict__ AcOut,         // natural fp32 layout (final iter), else null
    const float* __restrict__ adj,
    const float* __restrict__ ddera, const float* __restrict__ uoda,
    const float* __restrict__ coefP, const float* __restrict__ m8f) {
    __shared__ ushort T[8 * 1032];     // T[dc][i] = S[b, i, c0+dc], stride 1032 (bank-spread)
    __shared__ float dd_s[Nn];
    __shared__ float q_s[Nn];
    int n = blockIdx.x;
    int xcd = n & 7, idx = n >> 3;
    int rb = idx & 127;
    int b = ((idx >> 7) << 3) | xcd;   // batch: same XCD for all 128 rb-blocks of a batch
    int c0 = rb * 8;
    int t = threadIdx.x;
    if (t < 256) {
        *(float4*)(&dd_s[t << 2]) = *(const float4*)(ddera + b * Nn + (t << 2));
        *(float4*)(&q_s[t << 2])  = *(const float4*)(uoda + b * Nn + (t << 2));
    }
    const size_t mb = (size_t)b * Nn * Nn;
    if (Ssrc) {
        const ushort* Sb_ = Ssrc + mb;
        // stage transpose slices: for each source panel jp, row rr: cols c0..c0+7
        // are 8 contiguous ushorts (16 B). 1024 chunks, 2 per thread.
        #pragma unroll
        for (int k = 0; k < 2; ++k) {
            int q = t + 512 * k;
            int jp = q >> 3, rr = q & 7;
            uint4 v = *(const uint4*)(Sb_ + (size_t)jp * 8192 + rr * 1024 + c0);
            int i = jp * 8 + rr;
            // scalar ushort writes; banks = (4*dc + 4*jp + (rr>>1)) & 31 -> 2-way (free)
            T[0 * 1032 + i] = (ushort)(v.x & 0xffffu);
            T[1 * 1032 + i] = (ushort)(v.x >> 16);
            T[2 * 1032 + i] = (ushort)(v.y & 0xffffu);
            T[3 * 1032 + i] = (ushort)(v.y >> 16);
            T[4 * 1032 + i] = (ushort)(v.z & 0xffffu);
            T[5 * 1032 + i] = (ushort)(v.z >> 16);
            T[6 * 1032 + i] = (ushort)(v.w & 0xffffu);
            T[7 * 1032 + i] = (ushort)(v.w >> 16);
        }
    }
    __syncthreads();

    float cP = coefP[b], m8 = m8f[b];
    int w = t >> 6, lane = t & 63;
    int gi = c0 + w;                   // this wave's global row
    const float* Arow = adj + mb + (size_t)gi * Nn;
    const ushort* Srow = Ssrc ? (Ssrc + mb + (size_t)rb * 8192 + (size_t)w * 1024) : (const ushort*)0;
    float ddi = dd_s[gi], qi_ = q_s[gi];
    float gb0 = cP * ddi;              // G = 2(s+tr) + gb0 + cP*ddj + mqi*qj
    float mqi = m8 * qi_;

    float Lv[2][8], Av[2][8];
    float mx = -3.4e38f;
    #pragma unroll
    for (int cc = 0; cc < 2; ++cc) {
        int j0 = cc * 512 + (lane << 3);   // 8 consecutive cols per lane
        float4 a0 = *(const float4*)(Arow + j0);
        float4 a1 = *(const float4*)(Arow + j0 + 4);
        float av[8] = {a0.x, a0.y, a0.z, a0.w, a1.x, a1.y, a1.z, a1.w};
        float sv[8], tv[8];
        if (Ssrc) {
            uint4 su = *(const uint4*)(Srow + j0);
            uint4 tu = *(const uint4*)(&T[w * 1032 + j0]);
            bf8_to_f32(su, sv);
            bf8_to_f32(tu, tv);
        } else {
            #pragma unroll
            for (int e = 0; e < 8; ++e) { sv[e] = 0.f; tv[e] = 0.f; }
        }
        float4 d0 = *(const float4*)(&dd_s[j0]);
        float4 d1 = *(const float4*)(&dd_s[j0 + 4]);
        float4 e0 = *(const float4*)(&q_s[j0]);
        float4 e1 = *(const float4*)(&q_s[j0 + 4]);
        float dv[8] = {d0.x, d0.y, d0.z, d0.w, d1.x, d1.y, d1.z, d1.w};
        float qv[8] = {e0.x, e0.y, e0.z, e0.w, e1.x, e1.y, e1.z, e1.w};
        #pragma unroll
        for (int e = 0; e < 8; ++e) {
            float G = 2.f * (sv[e] + tv[e]) + (gb0 + cP * dv[e] + mqi * qv[e]);
            float nmu = (j0 + e == gi) ? (-0.5f * MUf) : (-MUf);
            float L = fmaf(G, nmu, sv[e] + av[e]);
            Av[cc][e] = av[e];
            Lv[cc][e] = L;
            mx = fmaxf(mx, L);
        }
    }
    mx = wave_max(mx);
    float sum = 0.f;
    #pragma unroll
    for (int cc = 0; cc < 2; ++cc) {
        #pragma unroll
        for (int e = 0; e < 8; ++e) {
            float p = __expf(Lv[cc][e] - mx);
            Lv[cc][e] = p;
            sum += p;
        }
    }
    sum = wave_sum(sum);
    float inv = 1.0f / sum;

    if (AcOut) {
        // final: Ac = softmax * adj, natural fp32 layout
        float* drow = AcOut + mb + (size_t)gi * Nn;
        #pragma unroll
        for (int cc = 0; cc < 2; ++cc) {
            int j0 = cc * 512 + (lane << 3);
            float4 o0, o1;
            o0.x = Lv[cc][0] * inv * Av[cc][0];
            o0.y = Lv[cc][1] * inv * Av[cc][1];
            o0.z = Lv[cc][2] * inv * Av[cc][2];
            o0.w = Lv[cc][3] * inv * Av[cc][3];
            o1.x = Lv[cc][4] * inv * Av[cc][4];
            o1.y = Lv[cc][5] * inv * Av[cc][5];
            o1.z = Lv[cc][6] * inv * Av[cc][6];
            o1.w = Lv[cc][7] * inv * Av[cc][7];
            *(float4*)(drow + j0) = o0;
            *(float4*)(drow + j0 + 4) = o1;
        }
    } else {
        // S = Ac - adj = a*(p*inv - 1), bf16, own-row contiguous store
        ushort* drow = Sdst + mb + (size_t)rb * 8192 + (size_t)w * 1024;
        #pragma unroll
        for (int cc = 0; cc < 2; ++cc) {
            int j0 = cc * 512 + (lane << 3);
            float s[8];
            #pragma unroll
            for (int e = 0; e < 8; ++e)
                s[e] = Av[cc][e] * fmaf(Lv[cc][e], inv, -1.0f);
            uint4 o;
            o.x = pack2(s[0], s[1]);
            o.y = pack2(s[2], s[3]);
            o.z = pack2(s[4], s[5]);
            o.w = pack2(s[6], s[7]);
            *(uint4*)(drow + j0) = o;
        }
    }
}

extern "C" void kernel_launch(void* const* d_in, const int* in_sizes, int n_in,
                              void* d_out, int out_size, void* d_ws, size_t ws_size,
                              hipStream_t stream) {
    const float* x = (const float*)d_in[0];
    const float* adj = (const float*)d_in[1];
    const float* s_in = (const float*)d_in[2];
    float* out = (float*)d_out;
    float* ws = (float*)d_ws;

    ushort* Sa = (ushort*)ws;              // MAT ushorts (64 MiB), bf16 panel layout
    ushort* Sb2 = Sa + (size_t)MAT;        // MAT ushorts (64 MiB)
    float* pp = ws;                        // pool partials alias Sa (consumed before S written)
    float* vb = ws + (size_t)MAT;          // same float offset as before (2*MAT ushorts == MAT floats)
    float* dflat = vb + 0 * (size_t)Vv;
    float* s0 = vb + 1 * (size_t)Vv;
    float* s1 = vb + 2 * (size_t)Vv;
    float* u  = vb + 3 * (size_t)Vv;
    float* uod = vb + 4 * (size_t)Vv;
    float* d2 = vb + 5 * (size_t)Vv;
    float* dder = vb + 6 * (size_t)Vv;
    float* r1 = vb + 7 * (size_t)Vv;
    float* r2 = vb + 8 * (size_t)Vv;
    float* q1 = vb + 9 * (size_t)Vv;
    float* q2 = vb + 10 * (size_t)Vv;
    float* coefP = vb + 11 * (size_t)Vv;
    float* m8f = coefP + 32;
    float* mcp = coefP + 64;
    float* orp = coefP + 96;
    float* outAc = out + AC_OFF;

    k_rowsumvec<<<8192, 256, 0, stream>>>(adj, s_in, dflat, s0, s1, u, uod, d2, dder);
    k_matvec<<<8192, 256, 0, stream>>>(adj, uod, u, s0, s1, r1, r2, q1, q2);
    k_batchred<<<32, 256, 0, stream>>>(dflat, s0, s1, u, uod, d2, r1, r2, q1, q2,
                                       out, coefP, m8f, mcp, orp);
    k_final<<<1, 64, 0, stream>>>(mcp, orp, out);
    k_pool_a<<<dim3(64, 32), 128, 0, stream>>>(x, s0, s1, pp);
    k_pool_b<<<32, 256, 0, stream>>>(pp, out);

    // 5 rewiring iterations; S (bf16) ping-pongs Sa <-> Sb2; final writes fp32 Ac.
    k_iter<<<4096, 512, 0, stream>>>(nullptr, Sa, nullptr, adj, dder, uod, coefP, m8f);
    k_iter<<<4096, 512, 0, stream>>>(Sa, Sb2, nullptr, adj, dder, uod, coefP, m8f);
    k_iter<<<4096, 512, 0, stream>>>(Sb2, Sa, nullptr, adj, dder, uod, coefP, m8f);
    k_iter<<<4096, 512, 0, stream>>>(Sa, Sb2, nullptr, adj, dder, uod, coefP, m8f);
    k_iter<<<4096, 512, 0, stream>>>(Sb2, nullptr, outAc, adj, dder, uod, coefP, m8f);
}

// Round 2
// 551.127 us; speedup vs baseline: 1.1365x; 1.0639x over previous
//
#include <hip/hip_runtime.h>
#include <cstddef>

#define Nn 1024
#define Bb 32
#define Ff 128
#define Vv 32768            // B*N
#define MAT 33554432        // B*N*N
#define OUT_OFF 0
#define AC_OFF 8192
#define OA_OFF (8192 + 33554432)
#define MC_OFF (OA_OFF + 128)
#define OR_OFF (MC_OFF + 1)
#define EPSf 1e-15f
#define MUf 0.01f

__device__ __forceinline__ float wave_sum(float v) {
    #pragma unroll
    for (int off = 32; off; off >>= 1) v += __shfl_xor(v, off, 64);
    return v;
}
__device__ __forceinline__ float wave_max(float v) {
    #pragma unroll
    for (int off = 32; off; off >>= 1) v = fmaxf(v, __shfl_xor(v, off, 64));
    return v;
}

// bf16 helpers (RNE pack, exact expand)
__device__ __forceinline__ ushort f2bf(float f) {
    unsigned u = __float_as_uint(f);
    u = (u + 0x7fffu + ((u >> 16) & 1u)) >> 16;
    return (ushort)u;
}
__device__ __forceinline__ unsigned pack2(float a, float b) {
    return (unsigned)f2bf(a) | ((unsigned)f2bf(b) << 16);
}
__device__ __forceinline__ void bf8_to_f32(uint4 v, float* f) {
    f[0] = __uint_as_float(v.x << 16); f[1] = __uint_as_float(v.x & 0xffff0000u);
    f[2] = __uint_as_float(v.y << 16); f[3] = __uint_as_float(v.y & 0xffff0000u);
    f[4] = __uint_as_float(v.z << 16); f[5] = __uint_as_float(v.z & 0xffff0000u);
    f[6] = __uint_as_float(v.w << 16); f[7] = __uint_as_float(v.w & 0xffff0000u);
}

// ---- K1: row sums of adj -> d_flat, fused per-node vectors + bf16 adj copy ----
__global__ void k_rowsumvec(const float* __restrict__ adj, const float* __restrict__ s_in,
                            float* __restrict__ dflat,
                            float* __restrict__ s0a, float* __restrict__ s1a,
                            float* __restrict__ ua, float* __restrict__ uoda,
                            float* __restrict__ d2a, float* __restrict__ ddera,
                            ushort* __restrict__ adjBF) {
    int w = threadIdx.x >> 6, lane = threadIdx.x & 63;
    int row = blockIdx.x * 4 + w;          // 0..32767
    const float* r = adj + (size_t)row * Nn;
    ushort* rb = adjBF + (size_t)row * Nn;
    float acc = 0.f;
    #pragma unroll
    for (int cc = 0; cc < 4; ++cc) {
        int j0 = cc * 256 + (lane << 2);
        float4 v = *(const float4*)(r + j0);
        acc += v.x + v.y + v.z + v.w;
        uint2 o;
        o.x = pack2(v.x, v.y);
        o.y = pack2(v.z, v.w);
        *(uint2*)(rb + j0) = o;
    }
    acc = wave_sum(acc);
    if (lane == 0) {
        float df = acc;
        dflat[row] = df;
        float l0 = s_in[2 * row], l1 = s_in[2 * row + 1];
        float m = fmaxf(l0, l1);
        float e0 = __expf(l0 - m), e1 = __expf(l1 - m);
        float Z = e0 + e1;
        s0a[row] = e0 / Z; s1a[row] = e1 / Z;
        float u = (l1 > l0) ? -0.03125f : 0.03125f;
        float d2 = sqrtf(df + EPSf) + EPSf;
        float uod = u / d2;
        ua[row] = u; uoda[row] = uod; d2a[row] = d2;
        ddera[row] = -0.5f * d2 / (df + EPSf);
    }
}

// ---- K3: per-row matvecs r1=A.uod r2=A.u q1=A.s0 q2=A.s1. wave per row ----
__global__ void k_matvec(const float* __restrict__ adj,
                         const float* __restrict__ uoda, const float* __restrict__ ua,
                         const float* __restrict__ s0a, const float* __restrict__ s1a,
                         float* __restrict__ r1a, float* __restrict__ r2a,
                         float* __restrict__ q1a, float* __restrict__ q2a) {
    int w = threadIdx.x >> 6, lane = threadIdx.x & 63;
    int row = blockIdx.x * 4 + w;
    int b = row >> 10;
    const float* r = adj + (size_t)row * Nn;
    const float* uodB = uoda + b * Nn;
    const float* uB = ua + b * Nn;
    const float* s0B = s0a + b * Nn;
    const float* s1B = s1a + b * Nn;
    float a1 = 0.f, a2 = 0.f, a3 = 0.f, a4 = 0.f;
    #pragma unroll
    for (int cc = 0; cc < 4; ++cc) {
        int j0 = cc * 256 + (lane << 2);
        float4 av = *(const float4*)(r + j0);
        float4 uo = *(const float4*)(uodB + j0);
        float4 uu = *(const float4*)(uB + j0);
        float4 v0 = *(const float4*)(s0B + j0);
        float4 v1 = *(const float4*)(s1B + j0);
        a1 += av.x * uo.x + av.y * uo.y + av.z * uo.z + av.w * uo.w;
        a2 += av.x * uu.x + av.y * uu.y + av.z * uu.z + av.w * uu.w;
        a3 += av.x * v0.x + av.y * v0.y + av.z * v0.z + av.w * v0.w;
        a4 += av.x * v1.x + av.y * v1.y + av.z * v1.z + av.w * v1.w;
    }
    a1 = wave_sum(a1); a2 = wave_sum(a2); a3 = wave_sum(a3); a4 = wave_sum(a4);
    if (lane == 0) { r1a[row] = a1; r2a[row] = a2; q1a[row] = a3; q2a[row] = a4; }
}

// ---- K4: per-batch reductions -> f, coefP, m8f, out_adj, loss parts ----
__global__ void k_batchred(const float* __restrict__ dflat, const float* __restrict__ s0a,
                           const float* __restrict__ s1a, const float* __restrict__ ua,
                           const float* __restrict__ uoda, const float* __restrict__ d2a,
                           const float* __restrict__ r1a, const float* __restrict__ r2a,
                           const float* __restrict__ q1a, const float* __restrict__ q2a,
                           float* __restrict__ outp, float* __restrict__ coefP,
                           float* __restrict__ m8f, float* __restrict__ mcp,
                           float* __restrict__ orp) {
    int b = blockIdx.x, t = threadIdx.x;
    int base = b * Nn;
    float acc[13];
    #pragma unroll
    for (int k = 0; k < 13; ++k) acc[k] = 0.f;
    for (int i = t; i < Nn; i += 256) {
        float u = ua[base + i], uod = uoda[base + i], df = dflat[base + i], d2 = d2a[base + i];
        float r1 = r1a[base + i], r2 = r2a[base + i], q1 = q1a[base + i], q2 = q2a[base + i];
        float s0 = s0a[base + i], s1 = s1a[base + i];
        acc[0] += u * r1;
        acc[1] += uod * r2;
        acc[2] += df * uod * uod;
        acc[3] += uod * r1;
        acc[4] += d2 * d2 * (1.0f / 1024.0f);
        acc[5] += s0 * q1;
        acc[6] += s0 * q2;
        acc[7] += s1 * q1;
        acc[8] += s1 * q2;
        acc[9] += df * (s0 * s0 + s1 * s1);
        acc[10] += s0 * s0;
        acc[11] += s0 * s1;
        acc[12] += s1 * s1;
    }
    __shared__ float red[4][13];
    int w = t >> 6, lane = t & 63;
    #pragma unroll
    for (int k = 0; k < 13; ++k) {
        acc[k] = wave_sum(acc[k]);
        if (lane == 0) red[w][k] = acc[k];
    }
    __syncthreads();
    if (t == 0) {
        float v[13];
        #pragma unroll
        for (int k = 0; k < 13; ++k) v[k] = red[0][k] + red[1][k] + red[2][k] + red[3][k];
        float num = v[2] - v[3];
        float f = 1024.0f * fabsf(num / (v[4] + EPSf));
        float as = v[0] + v[1];
        coefP[b] = -4.0f * f * as;
        m8f[b] = -8.0f * f;
        outp[OA_OFF + b * 4 + 0] = v[5];
        outp[OA_OFF + b * 4 + 1] = v[6];
        outp[OA_OFF + b * 4 + 2] = v[7];
        outp[OA_OFF + b * 4 + 3] = v[8];
        mcp[b] = -((v[5] + v[8]) / v[9]);
        float ss00 = v[10], ss01 = v[11], ss11 = v[12];
        float nrm = sqrtf(ss00 * ss00 + 2.f * ss01 * ss01 + ss11 * ss11);
        float is = 0.7071067811865475f;
        float d00 = ss00 / nrm - is, d01 = ss01 / nrm, d11 = ss11 / nrm - is;
        orp[b] = sqrtf(d00 * d00 + 2.f * d01 * d01 + d11 * d11);
    }
}

// ---- K4b: average loss parts ----
__global__ void k_final(const float* __restrict__ mcp, const float* __restrict__ orp,
                        float* __restrict__ outp) {
    int t = threadIdx.x;  // 64
    float m = (t < 32) ? mcp[t] : 0.f;
    float o = (t < 32) ? orp[t] : 0.f;
    m = wave_sum(m); o = wave_sum(o);
    if (t == 0) { outp[MC_OFF] = m * (1.0f / 32.0f); outp[OR_OFF] = o * (1.0f / 32.0f); }
}

// ---- K5a: pooled feature partials. 64 chunks of 16 rows per batch ----
__global__ void k_pool_a(const float* __restrict__ x, const float* __restrict__ s0a,
                         const float* __restrict__ s1a, float* __restrict__ pp) {
    int c = blockIdx.x, b = blockIdx.y, f = threadIdx.x;  // 64 x 32, 128 threads
    const float* xb = x + (size_t)b * Nn * Ff;
    float a0 = 0.f, a1 = 0.f;
    int n0 = c * 16;
    #pragma unroll 4
    for (int n = n0; n < n0 + 16; ++n) {
        float xv = xb[(size_t)n * Ff + f];
        a0 += s0a[b * Nn + n] * xv;
        a1 += s1a[b * Nn + n] * xv;
    }
    pp[((size_t)(b * 64 + c) * 2 + 0) * Ff + f] = a0;
    pp[((size_t)(b * 64 + c) * 2 + 1) * Ff + f] = a1;
}

// ---- K5b: reduce pooled partials -> d_out ----
__global__ void k_pool_b(const float* __restrict__ pp, float* __restrict__ outp) {
    int b = blockIdx.x, t = threadIdx.x;  // 256
    int k = t >> 7, f = t & 127;
    float acc = 0.f;
    #pragma unroll
    for (int c = 0; c < 64; ++c) acc += pp[((size_t)(b * 64 + c) * 2 + k) * Ff + f];
    outp[OUT_OFF + b * 256 + k * Ff + f] = acc;
}

// ---- K6: one rewiring iteration.
// S = Ac - adj in BF16 panel layout:
//   S[b,i,j] at ushort index b*N*N + (i>>3)*8192 + (i&7)*1024 + j
// Iters 1-4 read BF16 adj (natural layout, scratch in d_out Ac region) so the
// whole working set (adjBF 64 + Ssrc 64 + Sdst 64 = 192 MiB) is L3-resident.
// Final iter reads fp32 adj (exact output path) and writes fp32 Ac natural.
// Only transpose slices T staged in LDS; one barrier.
__global__ __launch_bounds__(512, 6) void k_iter(
    const ushort* __restrict__ Ssrc,   // bf16 panel layout; null on iter 1
    ushort* __restrict__ Sdst,         // bf16 panel layout (iters 1-4)
    float* __restrict__ AcOut,         // natural fp32 layout (final iter), else null
    const ushort* __restrict__ adjBF,  // bf16 natural layout (iters 1-4)
    const float* __restrict__ adjF,    // fp32 natural layout (final iter)
    const float* __restrict__ ddera, const float* __restrict__ uoda,
    const float* __restrict__ coefP, const float* __restrict__ m8f) {
    __shared__ ushort T[8 * 1032];     // T[dc][i] = S[b, i, c0+dc], stride 1032 (bank-spread)
    __shared__ float dd_s[Nn];
    __shared__ float q_s[Nn];
    int n = blockIdx.x;
    int xcd = n & 7, idx = n >> 3;
    int rb = idx & 127;
    int b = ((idx >> 7) << 3) | xcd;   // batch: same XCD for all 128 rb-blocks of a batch
    int c0 = rb * 8;
    int t = threadIdx.x;
    if (t < 256) {
        *(float4*)(&dd_s[t << 2]) = *(const float4*)(ddera + b * Nn + (t << 2));
        *(float4*)(&q_s[t << 2])  = *(const float4*)(uoda + b * Nn + (t << 2));
    }
    const size_t mb = (size_t)b * Nn * Nn;
    if (Ssrc) {
        const ushort* Sb_ = Ssrc + mb;
        #pragma unroll
        for (int k = 0; k < 2; ++k) {
            int q = t + 512 * k;
            int jp = q >> 3, rr = q & 7;
            uint4 v = *(const uint4*)(Sb_ + (size_t)jp * 8192 + rr * 1024 + c0);
            int i = jp * 8 + rr;
            T[0 * 1032 + i] = (ushort)(v.x & 0xffffu);
            T[1 * 1032 + i] = (ushort)(v.x >> 16);
            T[2 * 1032 + i] = (ushort)(v.y & 0xffffu);
            T[3 * 1032 + i] = (ushort)(v.y >> 16);
            T[4 * 1032 + i] = (ushort)(v.z & 0xffffu);
            T[5 * 1032 + i] = (ushort)(v.z >> 16);
            T[6 * 1032 + i] = (ushort)(v.w & 0xffffu);
            T[7 * 1032 + i] = (ushort)(v.w >> 16);
        }
    }
    __syncthreads();

    float cP = coefP[b], m8 = m8f[b];
    int w = t >> 6, lane = t & 63;
    int gi = c0 + w;                   // this wave's global row
    const ushort* ArowB = adjBF + mb + (size_t)gi * Nn;
    const float* ArowF = adjF + mb + (size_t)gi * Nn;
    const ushort* Srow = Ssrc ? (Ssrc + mb + (size_t)rb * 8192 + (size_t)w * 1024) : (const ushort*)0;
    float ddi = dd_s[gi], qi_ = q_s[gi];
    float gb0 = cP * ddi;              // G = 2(s+tr) + gb0 + cP*ddj + mqi*qj
    float mqi = m8 * qi_;

    float Lv[2][8], Av[2][8];
    float mx = -3.4e38f;
    #pragma unroll
    for (int cc = 0; cc < 2; ++cc) {
        int j0 = cc * 512 + (lane << 3);   // 8 consecutive cols per lane
        float av[8];
        if (AcOut) {
            float4 a0 = *(const float4*)(ArowF + j0);
            float4 a1 = *(const float4*)(ArowF + j0 + 4);
            av[0] = a0.x; av[1] = a0.y; av[2] = a0.z; av[3] = a0.w;
            av[4] = a1.x; av[5] = a1.y; av[6] = a1.z; av[7] = a1.w;
        } else {
            uint4 au = *(const uint4*)(ArowB + j0);
            bf8_to_f32(au, av);
        }
        float sv[8], tv[8];
        if (Ssrc) {
            uint4 su = *(const uint4*)(Srow + j0);
            uint4 tu = *(const uint4*)(&T[w * 1032 + j0]);
            bf8_to_f32(su, sv);
            bf8_to_f32(tu, tv);
        } else {
            #pragma unroll
            for (int e = 0; e < 8; ++e) { sv[e] = 0.f; tv[e] = 0.f; }
        }
        float4 d0 = *(const float4*)(&dd_s[j0]);
        float4 d1 = *(const float4*)(&dd_s[j0 + 4]);
        float4 e0 = *(const float4*)(&q_s[j0]);
        float4 e1 = *(const float4*)(&q_s[j0 + 4]);
        float dv[8] = {d0.x, d0.y, d0.z, d0.w, d1.x, d1.y, d1.z, d1.w};
        float qv[8] = {e0.x, e0.y, e0.z, e0.w, e1.x, e1.y, e1.z, e1.w};
        #pragma unroll
        for (int e = 0; e < 8; ++e) {
            float G = 2.f * (sv[e] + tv[e]) + (gb0 + cP * dv[e] + mqi * qv[e]);
            float nmu = (j0 + e == gi) ? (-0.5f * MUf) : (-MUf);
            float L = fmaf(G, nmu, sv[e] + av[e]);
            Av[cc][e] = av[e];
            Lv[cc][e] = L;
            mx = fmaxf(mx, L);
        }
    }
    mx = wave_max(mx);
    float sum = 0.f;
    #pragma unroll
    for (int cc = 0; cc < 2; ++cc) {
        #pragma unroll
        for (int e = 0; e < 8; ++e) {
            float p = __expf(Lv[cc][e] - mx);
            Lv[cc][e] = p;
            sum += p;
        }
    }
    sum = wave_sum(sum);
    float inv = 1.0f / sum;

    if (AcOut) {
        // final: Ac = softmax * adj, natural fp32 layout
        float* drow = AcOut + mb + (size_t)gi * Nn;
        #pragma unroll
        for (int cc = 0; cc < 2; ++cc) {
            int j0 = cc * 512 + (lane << 3);
            float4 o0, o1;
            o0.x = Lv[cc][0] * inv * Av[cc][0];
            o0.y = Lv[cc][1] * inv * Av[cc][1];
            o0.z = Lv[cc][2] * inv * Av[cc][2];
            o0.w = Lv[cc][3] * inv * Av[cc][3];
            o1.x = Lv[cc][4] * inv * Av[cc][4];
            o1.y = Lv[cc][5] * inv * Av[cc][5];
            o1.z = Lv[cc][6] * inv * Av[cc][6];
            o1.w = Lv[cc][7] * inv * Av[cc][7];
            *(float4*)(drow + j0) = o0;
            *(float4*)(drow + j0 + 4) = o1;
        }
    } else {
        // S = Ac - adj = a*(p*inv - 1), bf16, own-row contiguous store
        ushort* drow = Sdst + mb + (size_t)rb * 8192 + (size_t)w * 1024;
        #pragma unroll
        for (int cc = 0; cc < 2; ++cc) {
            int j0 = cc * 512 + (lane << 3);
            float s[8];
            #pragma unroll
            for (int e = 0; e < 8; ++e)
                s[e] = Av[cc][e] * fmaf(Lv[cc][e], inv, -1.0f);
            uint4 o;
            o.x = pack2(s[0], s[1]);
            o.y = pack2(s[2], s[3]);
            o.z = pack2(s[4], s[5]);
            o.w = pack2(s[6], s[7]);
            *(uint4*)(drow + j0) = o;
        }
    }
}

extern "C" void kernel_launch(void* const* d_in, const int* in_sizes, int n_in,
                              void* d_out, int out_size, void* d_ws, size_t ws_size,
                              hipStream_t stream) {
    const float* x = (const float*)d_in[0];
    const float* adj = (const float*)d_in[1];
    const float* s_in = (const float*)d_in[2];
    float* out = (float*)d_out;
    float* ws = (float*)d_ws;

    ushort* Sa = (ushort*)ws;              // MAT ushorts (64 MiB), bf16 panel layout
    ushort* Sb2 = Sa + (size_t)MAT;        // MAT ushorts (64 MiB)
    float* pp = ws;                        // pool partials alias Sa (consumed before S written)
    float* vb = ws + (size_t)MAT;          // (2*MAT ushorts == MAT floats)
    float* dflat = vb + 0 * (size_t)Vv;
    float* s0 = vb + 1 * (size_t)Vv;
    float* s1 = vb + 2 * (size_t)Vv;
    float* u  = vb + 3 * (size_t)Vv;
    float* uod = vb + 4 * (size_t)Vv;
    float* d2 = vb + 5 * (size_t)Vv;
    float* dder = vb + 6 * (size_t)Vv;
    float* r1 = vb + 7 * (size_t)Vv;
    float* r2 = vb + 8 * (size_t)Vv;
    float* q1 = vb + 9 * (size_t)Vv;
    float* q2 = vb + 10 * (size_t)Vv;
    float* coefP = vb + 11 * (size_t)Vv;
    float* m8f = coefP + 32;
    float* mcp = coefP + 64;
    float* orp = coefP + 96;
    float* outAc = out + AC_OFF;
    // bf16 adj scratch lives in the d_out Ac region (only written by iter 5,
    // which reads fp32 adj instead of adjBF -> no alias hazard).
    ushort* adjBF = (ushort*)outAc;

    k_rowsumvec<<<8192, 256, 0, stream>>>(adj, s_in, dflat, s0, s1, u, uod, d2, dder, adjBF);
    k_matvec<<<8192, 256, 0, stream>>>(adj, uod, u, s0, s1, r1, r2, q1, q2);
    k_batchred<<<32, 256, 0, stream>>>(dflat, s0, s1, u, uod, d2, r1, r2, q1, q2,
                                       out, coefP, m8f, mcp, orp);
    k_final<<<1, 64, 0, stream>>>(mcp, orp, out);
    k_pool_a<<<dim3(64, 32), 128, 0, stream>>>(x, s0, s1, pp);
    k_pool_b<<<32, 256, 0, stream>>>(pp, out);

    // 5 rewiring iterations; S (bf16) ping-pongs Sa <-> Sb2; final writes fp32 Ac.
    k_iter<<<4096, 512, 0, stream>>>(nullptr, Sa, nullptr, adjBF, adj, dder, uod, coefP, m8f);
    k_iter<<<4096, 512, 0, stream>>>(Sa, Sb2, nullptr, adjBF, adj, dder, uod, coefP, m8f);
    k_iter<<<4096, 512, 0, stream>>>(Sb2, Sa, nullptr, adjBF, adj, dder, uod, coefP, m8f);
    k_iter<<<4096, 512, 0, stream>>>(Sa, Sb2, nullptr, adjBF, adj, dder, uod, coefP, m8f);
    k_iter<<<4096, 512, 0, stream>>>(Sb2, nullptr, outAc, adjBF, adj, dder, uod, coefP, m8f);
}